// Round 12
// baseline (482.171 us; speedup 1.0000x reference)
//
#include <hip/hip_runtime.h>
#include <cmath>

// Problem constants: S=16384, IN_DIM=1024, D=6400, BINS=20
#define S_DIM 16384
#define K_DIM 1024
#define D_DIM 6400
#define NBINS 20
#define HSTRIDE 21   // shist column stride (pad 20->21: spreads banks)

using half_t = _Float16;
using half8  = __attribute__((ext_vector_type(8))) _Float16;
using f32x4  = __attribute__((ext_vector_type(4))) float;

// ------- fp32 -> fp16 convert + d_out zeroing, coalesced (R11, keep) ------
__global__ __launch_bounds__(256) void cvt_fused(
    const float4* __restrict__ x4, unsigned long long* __restrict__ xh8, int n4x,
    const float4* __restrict__ w4, unsigned long long* __restrict__ wh8, int n4w,
    float4* __restrict__ z, int nz4) {
  const int stride = gridDim.x * blockDim.x;
  int tid = blockIdx.x * blockDim.x + threadIdx.x;
  for (int i = tid; i < nz4; i += stride)
    z[i] = (float4){0.f, 0.f, 0.f, 0.f};          // histogram accumulator
  for (int i = tid; i < n4x; i += stride) {
    float4 v = x4[i];
    union { half_t h[4]; unsigned long long u; } c;
    c.h[0] = (half_t)v.x; c.h[1] = (half_t)v.y;
    c.h[2] = (half_t)v.z; c.h[3] = (half_t)v.w;
    xh8[i] = c.u;
  }
  for (int i = tid; i < n4w; i += stride) {
    float4 v = w4[i];
    union { half_t h[4]; unsigned long long u; } c;
    c.h[0] = (half_t)v.x; c.h[1] = (half_t)v.y;
    c.h[2] = (half_t)v.z; c.h[3] = (half_t)v.w;
    wh8[i] = c.u;
  }
}

#define VMWAIT(N) __asm__ volatile("s_waitcnt vmcnt(" #N ")" ::: "memory")
#define BAR()     __asm__ volatile("s_barrier" ::: "memory")
#define SP1()     __builtin_amdgcn_s_setprio(1)
#define SP0()     __builtin_amdgcn_s_setprio(0)

#define GLL(SRC, DST) __builtin_amdgcn_global_load_lds(                      \
    (const __attribute__((address_space(1))) void*)(SRC),                    \
    (__attribute__((address_space(3))) void*)(DST), 16, 0, 0)

// -- fused GEMM + histogram, 256x256, 8-wave, BK=64, B-DIRECT-from-global --
// R11 post-mortem: R8's wall is ADDITIVE MFMA(2483cy) + LDS-read(3070cy)
// per tile per CU; schedule tricks don't overlap the pipes (5 structural
// attempts).  So SHRINK the LDS pipe: B operands load straight from global
// (W col-panel 512KB is L2-resident under the XCD swizzle) into registers,
// ONE FULL TILE ahead (~4500cy lead >> 225cy L2 latency -- fixes R4's
// sub-tile-lead failure).  LDS reads/tile: 256 -> 128 b128.  ldsB deleted.
// 8 waves / 512 thr (2M x 4N, per-wave C 128x64) because B-dbuf regs don't
// fit under the 128-VGPR/4-wave cap (acc 128 AGPR + B 32 + aF 32 + addr
// fits the 256 budget at 2 waves/SIMD).  MFMA clusters grow to 32/wait.
//
// Per tile t (A buf PB = t&1):
//   [stage A(t+1)->buf^1: 4 GLL]                                (step 1)
//   [8 ds_read aF ks0] [SP1 32 MFMA (aF,ks0 B-regs) SP0]        (step 2)
//   [8 ds_read aF ks1] [SP1 32 MFMA SP0]                        (step 3)
//   [load B(t+1): 8 x 16B reg-loads (compiler-tracked)]         (step 4)
//   [VMWAIT(8)] [BAR]                                           (step 5)
// Ledger: at step 5 outstanding = A(t+1) 4 GLL (older) + B(t+1) 8 (newer);
// vmcnt(8) retires exactly A(t+1).  B(t+1) stays in flight; the compiler's
// scoreboard inserts its own vmcnt before the first B-reg use at t+1
// (~1 tile of slack -> no stall).  RAW on A: VMWAIT(8)+BAR before t+1's
// ds_reads.  WAR on A stage: buf^1 last read at t-1, its end-BAR precedes
// step 1.  Tail t=15: no stage/loads, VMWAIT(0).
// A LDS swizzle: identical to R8 (128B rows, chunk (4ks+quad)^(l16&7) on
// read; source chunk (t&7)^((t>>3)&7), linear GLL dest; measured
// conflict-free -- counter = hist floor 8567313).
__global__ __launch_bounds__(512, 2) void gemm_hist256(
    const half_t* __restrict__ xh, const half_t* __restrict__ wh,
    const float* __restrict__ mins, const float* __restrict__ maxs,
    int* __restrict__ ghist)
{
  __shared__ __align__(16) char ldsA[2 * 32768];   // 2 bufs x 256 rows x 128 B
  __shared__ int shist[256 * HSTRIDE];             // 21.5 KB (total 85.5 KB)

  const int t    = threadIdx.x;
  const int lane = t & 63;
  const int wv   = t >> 6;           // 0..7
  const int wm   = wv >> 2;          // 0..1  (row half: 128 rows)
  const int wn   = wv & 3;           // 0..3  (col quarter: 64 cols)
  const int l16  = lane & 15;
  const int quad = lane >> 4;

  // XCD-aware bijective swizzle: 1600 blocks = 8 XCDs x 200
  const int bid = blockIdx.x;
  const int wg  = (bid & 7) * 200 + (bid >> 3);
  const int ct  = wg / 64;                 // 0..24 col-tiles
  const int rt  = wg - ct * 64;            // 0..63 row-tiles
  const int colBase = ct * 256;
  const int rowBase = rt * 256;

  for (int i = t; i < 256 * HSTRIDE; i += 512) shist[i] = 0;

  // A fragment read bases (row = wm*128 + mf*16 + l16; row&7 == l16&7).
  const char* pA0 = ldsA + (wm * 128 + l16) * 128 + (((0 + quad) ^ (l16 & 7)) * 16);
  const char* pA1 = ldsA + (wm * 128 + l16) * 128 + (((4 + quad) ^ (l16 & 7)) * 16);

  // A staging: thread t owns linear 16B slot t of each 8KB quarter (64 rows);
  // 4 GLLs cover rows 0-63 / 64-127 / 128-191 / 192-255 (+64 rows keeps the
  // XOR key (row&7) unchanged).  Source chunk = (t&7)^((t>>3)&7).
  const int gOff = (t >> 3) * K_DIM + (((t & 7) ^ ((t >> 3) & 7)) * 8);  // elems
  const int wvD  = wv * 1024;   // wave-uniform LDS base (HW adds lane*16)
  const half_t* xS = xh + (size_t)rowBase * K_DIM + gOff;

  // B direct-load pointers (per nf): col = colBase + wn*64 + nf*16 + l16,
  // lane chunk = quad*8 elems; quads form one contiguous 64B line per col.
  // Advanced +64 elems per tile; ks=1 via +32-elem (64B) immediate.
  const half_t* wB0 = wh + (size_t)(colBase + wn * 64 +  0 + l16) * K_DIM + quad * 8;
  const half_t* wB1 = wh + (size_t)(colBase + wn * 64 + 16 + l16) * K_DIM + quad * 8;
  const half_t* wB2 = wh + (size_t)(colBase + wn * 64 + 32 + l16) * K_DIM + quad * 8;
  const half_t* wB3 = wh + (size_t)(colBase + wn * 64 + 48 + l16) * K_DIM + quad * 8;

  f32x4 acc[8][4];
#pragma unroll
  for (int m = 0; m < 8; ++m)
#pragma unroll
    for (int n = 0; n < 4; ++n) acc[m][n] = (f32x4){0.f, 0.f, 0.f, 0.f};

  half8 aF[8], bF[8];   // bF[ks*4+nf], single-buffered (1-tile lead)

#define LOADB()                                                              \
  {                                                                          \
    bF[0] = *(const half8*)(wB0);      bF[1] = *(const half8*)(wB1);         \
    bF[2] = *(const half8*)(wB2);      bF[3] = *(const half8*)(wB3);         \
    bF[4] = *(const half8*)(wB0 + 32); bF[5] = *(const half8*)(wB1 + 32);    \
    bF[6] = *(const half8*)(wB2 + 32); bF[7] = *(const half8*)(wB3 + 32);    \
    wB0 += 64; wB1 += 64; wB2 += 64; wB3 += 64;                              \
  }
#define MFMA32(KS)                                                           \
  _Pragma("unroll") for (int mf = 0; mf < 8; ++mf)                           \
  _Pragma("unroll") for (int nf = 0; nf < 4; ++nf)                           \
    acc[mf][nf] = __builtin_amdgcn_mfma_f32_16x16x32_f16(                    \
        aF[mf], bF[(KS) * 4 + nf], acc[mf][nf], 0, 0, 0);
#define STAGEA(PN)                                                           \
  {                                                                          \
    GLL(xStg,               ldsA + (PN) +         wvD);                      \
    GLL(xStg +  64 * K_DIM, ldsA + (PN) +  8192 + wvD);                      \
    GLL(xStg + 128 * K_DIM, ldsA + (PN) + 16384 + wvD);                      \
    GLL(xStg + 192 * K_DIM, ldsA + (PN) + 24576 + wvD);                      \
    xStg += 64;                                                              \
  }

  // Prologue: stage A(0)->buf0 (4 GLL), load B(0) (8 reg-loads);
  // VMWAIT(8) retires A(0) (B stays outstanding, scoreboard-interlocked).
  const half_t* xStg = xS;
  STAGEA(0);
  LOADB();
  VMWAIT(8); BAR();

  // PB = current A buf, PN = next.  STG: stage A(t+1).  DOB: load B(t+1).
#define TILE(PB, PN, STG, DOB, WAITE)                                        \
  {                                                                          \
    if (STG) STAGEA(PN);                                                     \
    _Pragma("unroll") for (int mf = 0; mf < 8; ++mf)                         \
      aF[mf] = *(const half8*)(pA0 + (PB) + mf * 2048);                      \
    SP1(); MFMA32(0); SP0();                                                 \
    _Pragma("unroll") for (int mf = 0; mf < 8; ++mf)                         \
      aF[mf] = *(const half8*)(pA1 + (PB) + mf * 2048);                      \
    SP1(); MFMA32(1); SP0();                                                 \
    if (DOB) LOADB();                                                        \
    WAITE; BAR();                                                            \
  }

  // 16 K-tiles; tiles 0..14 stage A(t+1) + load B(t+1); tile 15 computes.
#pragma unroll 1
  for (int it = 0; it < 7; ++it) {
    TILE(0,     32768, 1, 1, VMWAIT(8));
    TILE(32768, 0,     1, 1, VMWAIT(8));
  }
  TILE(0,     32768, 1, 1, VMWAIT(8));   // t=14 (stages A15, loads B15)
  TILE(32768, 0,     0, 0, VMWAIT(0));   // t=15

#undef TILE

  // Epilogue: bin 128 values/thread. torch.histc semantics: count iff
  // min<=v<=max; v==max -> last bin (trunc==floor since v-a>=0).
#pragma unroll
  for (int nf = 0; nf < 4; ++nf) {
    const int lc = wn * 64 + nf * 16 + l16;
    const float a = mins[colBase + lc], b = maxs[colBase + lc];
    const float sc = (float)NBINS / (b - a);
    int* colHist = &shist[lc * HSTRIDE];
#pragma unroll
    for (int mf = 0; mf < 8; ++mf) {
#pragma unroll
      for (int r = 0; r < 4; ++r) {
        float v = acc[mf][nf][r];
        if (v >= a && v <= b) {
          int bin = (int)((v - a) * sc);
          bin = bin > NBINS - 1 ? NBINS - 1 : bin;
          atomicAdd(&colHist[bin], 1);
        }
      }
    }
  }
  __syncthreads();
  for (int i = t; i < 256 * NBINS; i += 512) {
    int col = i / NBINS, bin = i - col * NBINS;
    int v = shist[col * HSTRIDE + bin];
    if (v) atomicAdd(&ghist[colBase * NBINS + i], v);
  }
}

// ---------------- fallback (no workspace): fp32-staged 128x128 tile -------
__global__ __launch_bounds__(256) void gemm_hist_fb(
    const float* __restrict__ xf, const float* __restrict__ wf,
    const float* __restrict__ mins, const float* __restrict__ maxs,
    int* __restrict__ ghist)
{
  __shared__ __align__(16) half_t ldsA[4096];
  __shared__ __align__(16) half_t ldsB[4096];
  __shared__ int shist[128 * HSTRIDE];

  const int t     = threadIdx.x;
  const int lane  = t & 63;
  const int wv    = t >> 6;
  const int waveM = wv >> 1;
  const int waveN = wv & 1;
  const int l16   = lane & 15;
  const int quad  = lane >> 4;
  const int colBase = blockIdx.x * 128;

  for (int i = t; i < 128 * HSTRIDE; i += 256) shist[i] = 0;

  float mn[4], mx[4], inv[4];
  int lcol[4];
#pragma unroll
  for (int nt = 0; nt < 4; ++nt) {
    int lc = waveN * 64 + nt * 16 + l16;
    lcol[nt] = lc;
    float a = mins[colBase + lc], b = maxs[colBase + lc];
    mn[nt] = a; mx[nt] = b;
    inv[nt] = (float)NBINS / (b - a);
  }

  int aOff[4], bOff[4];
#pragma unroll
  for (int mt = 0; mt < 4; ++mt) {
    int m = waveM * 64 + mt * 16 + l16;
    aOff[mt] = (m * 4 + (quad ^ ((m >> 1) & 3))) * 8;
  }
#pragma unroll
  for (int nt = 0; nt < 4; ++nt) {
    int n = waveN * 64 + nt * 16 + l16;
    bOff[nt] = (n * 4 + (quad ^ ((n >> 1) & 3))) * 8;
  }

  for (int rt = blockIdx.y; rt < S_DIM / 128; rt += gridDim.y) {
    const int rowBase = rt * 128;
    f32x4 acc[4][4];
#pragma unroll
    for (int mt = 0; mt < 4; ++mt)
#pragma unroll
      for (int nt = 0; nt < 4; ++nt) acc[mt][nt] = (f32x4){0.f, 0.f, 0.f, 0.f};

    for (int kt = 0; kt < K_DIM; kt += 32) {
      __syncthreads();
#pragma unroll
      for (int i = 0; i < 2; ++i) {
        const int seg = t + i * 256;
        const int row = seg >> 2;
        const int kch = (seg & 3) ^ ((row >> 1) & 3);
        const float* ga = xf + (size_t)(rowBase + row) * K_DIM + kt + kch * 8;
        float4 v0 = ((const float4*)ga)[0];
        float4 v1 = ((const float4*)ga)[1];
        half8 h = { (half_t)v0.x, (half_t)v0.y, (half_t)v0.z, (half_t)v0.w,
                    (half_t)v1.x, (half_t)v1.y, (half_t)v1.z, (half_t)v1.w };
        *(half8*)&ldsA[seg * 8] = h;
        const float* gb = wf + (size_t)(colBase + row) * K_DIM + kt + kch * 8;
        float4 u0 = ((const float4*)gb)[0];
        float4 u1 = ((const float4*)gb)[1];
        half8 g = { (half_t)u0.x, (half_t)u0.y, (half_t)u0.z, (half_t)u0.w,
                    (half_t)u1.x, (half_t)u1.y, (half_t)u1.z, (half_t)u1.w };
        *(half8*)&ldsB[seg * 8] = g;
      }
      __syncthreads();
      {
        half8 aFf[4], bFf[4];
#pragma unroll
        for (int mt = 0; mt < 4; ++mt) aFf[mt] = *(const half8*)&ldsA[aOff[mt]];
#pragma unroll
        for (int nt = 0; nt < 4; ++nt) bFf[nt] = *(const half8*)&ldsB[bOff[nt]];
#pragma unroll
        for (int mt = 0; mt < 4; ++mt)
#pragma unroll
          for (int nt = 0; nt < 4; ++nt)
            acc[mt][nt] = __builtin_amdgcn_mfma_f32_16x16x32_f16(
                aFf[mt], bFf[nt], acc[mt][nt], 0, 0, 0);
      }
    }

#pragma unroll
    for (int nt = 0; nt < 4; ++nt) {
      const float a = mn[nt], b = mx[nt], sc = inv[nt];
      int* colHist = &shist[lcol[nt] * HSTRIDE];
#pragma unroll
      for (int mt = 0; mt < 4; ++mt) {
#pragma unroll
        for (int r = 0; r < 4; ++r) {
          float v = acc[mt][nt][r];
          if (v >= a && v <= b) {
            int bin = (int)((v - a) * sc);
            bin = bin > NBINS - 1 ? NBINS - 1 : bin;
            atomicAdd(&colHist[bin], 1);
          }
        }
      }
    }
  }

  __syncthreads();
  for (int i = t; i < 128 * NBINS; i += 256) {
    int col = i / NBINS, bin = i - col * NBINS;
    int v = shist[col * HSTRIDE + bin];
    if (v) atomicAdd(&ghist[colBase * NBINS + i], v);
  }
}

// ---------------- L2 normalize per group of 20 bins (in place) ------------
__global__ void normalize_kernel(const int* __restrict__ hist, float* __restrict__ out) {
  int g = blockIdx.x * blockDim.x + threadIdx.x;
  if (g >= D_DIM) return;
  const int base = g * NBINS;
  float v[NBINS];
  float ss = 0.f;
#pragma unroll
  for (int i = 0; i < NBINS; ++i) { v[i] = (float)hist[base + i]; ss += v[i] * v[i]; }
  float sc = 1.0f / fmaxf(sqrtf(ss), 1e-12f);
#pragma unroll
  for (int i = 0; i < NBINS; ++i) out[base + i] = v[i] * sc;
}

extern "C" void kernel_launch(void* const* d_in, const int* in_sizes, int n_in,
                              void* d_out, int out_size, void* d_ws, size_t ws_size,
                              hipStream_t stream) {
  const float* x    = (const float*)d_in[0];
  const float* W    = (const float*)d_in[1];
  const float* mins = (const float*)d_in[2];
  const float* maxs = (const float*)d_in[3];
  float* out = (float*)d_out;

  const size_t xh_elems = (size_t)S_DIM * K_DIM;
  const size_t wh_elems = (size_t)D_DIM * K_DIM;
  const size_t need = (xh_elems + wh_elems) * sizeof(half_t);

  if (ws_size >= need) {
    half_t* xh = (half_t*)d_ws;
    half_t* wh = xh + xh_elems;
    int n4x = (int)(xh_elems / 4), n4w = (int)(wh_elems / 4);
    // cvt also zeroes d_out (re-poisoned 0xAA between runs)
    cvt_fused<<<2048, 256, 0, stream>>>(
        (const float4*)x, (unsigned long long*)xh, n4x,
        (const float4*)W, (unsigned long long*)wh, n4w,
        (float4*)d_out, out_size / 4);
    gemm_hist256<<<dim3(1600), 512, 0, stream>>>(xh, wh, mins, maxs, (int*)d_out);
  } else {
    hipMemsetAsync(d_out, 0, (size_t)out_size * sizeof(float), stream);
    gemm_hist_fb<<<dim3(D_DIM / 128, 64), 256, 0, stream>>>(
        x, W, mins, maxs, (int*)d_out);
  }

  normalize_kernel<<<(D_DIM + 255) / 256, 256, 0, stream>>>((int*)d_out, out);
}

// Round 13
// 352.703 us; speedup vs baseline: 1.3671x; 1.3671x over previous
//
#include <hip/hip_runtime.h>
#include <cmath>

// Problem constants: S=16384, IN_DIM=1024, D=6400, BINS=20
#define S_DIM 16384
#define K_DIM 1024
#define D_DIM 6400
#define NBINS 20
#define HSTRIDE 21   // shist column stride (pad 20->21: spreads banks)

using half_t = _Float16;
using half8  = __attribute__((ext_vector_type(8))) _Float16;
using f32x4  = __attribute__((ext_vector_type(4))) float;

// ------- fp32 -> fp16 convert + d_out zeroing, coalesced (R11, keep) ------
__global__ __launch_bounds__(256) void cvt_fused(
    const float4* __restrict__ x4, unsigned long long* __restrict__ xh8, int n4x,
    const float4* __restrict__ w4, unsigned long long* __restrict__ wh8, int n4w,
    float4* __restrict__ z, int nz4) {
  const int stride = gridDim.x * blockDim.x;
  int tid = blockIdx.x * blockDim.x + threadIdx.x;
  for (int i = tid; i < nz4; i += stride)
    z[i] = (float4){0.f, 0.f, 0.f, 0.f};          // histogram accumulator
  for (int i = tid; i < n4x; i += stride) {
    float4 v = x4[i];
    union { half_t h[4]; unsigned long long u; } c;
    c.h[0] = (half_t)v.x; c.h[1] = (half_t)v.y;
    c.h[2] = (half_t)v.z; c.h[3] = (half_t)v.w;
    xh8[i] = c.u;
  }
  for (int i = tid; i < n4w; i += stride) {
    float4 v = w4[i];
    union { half_t h[4]; unsigned long long u; } c;
    c.h[0] = (half_t)v.x; c.h[1] = (half_t)v.y;
    c.h[2] = (half_t)v.z; c.h[3] = (half_t)v.w;
    wh8[i] = c.u;
  }
}

#define VMWAIT0() __asm__ volatile("s_waitcnt vmcnt(0)" ::: "memory")
#define BAR()     __asm__ volatile("s_barrier" ::: "memory")
#define SP1()     __builtin_amdgcn_s_setprio(1)
#define SP0()     __builtin_amdgcn_s_setprio(0)

#define GLL(SRC, DST) __builtin_amdgcn_global_load_lds(                      \
    (const __attribute__((address_space(1))) void*)(SRC),                    \
    (__attribute__((address_space(3))) void*)(DST), 16, 0, 0)

// ------- fused GEMM + histogram, 256x256, 16-wave, BK=64 (R8, BEST) -------
// Session optimum: 245 us main kernel, 876 TF, MfmaUtil 39.6.  The wall is
// ADDITIVE MFMA(2483cy) + LDS-read(~3070cy) per BK64-tile per CU; closed
// experiment arcs: overlap-the-pipes (R1 8-phase 287, R9 sandwich 277,
// R7 4-deep 255, R10 2-blocks/CU 287) and shrink-the-LDS-pipe-via-global
// (R4 397, R12 376) all regressed vs this minimal-sync schedule.
// Schedule per K-tile: [stage {A,B}(t+1): 4 GLL] [8 ds_read ks0]
// [SP1 16-MFMA SP0] [8 ds_read ks1] [SP1 16-MFMA SP0] [vmcnt(0); BAR].
// RAW: tile t staged during t-1, retired by t-1's VMWAIT0 + end-BAR.
// WAR: stage at t overwrites buf[(t+1)&1], last read at t-1; those reads
// are lgkm-retired before each wave's pre-end-BAR MFMAs.
// LDS swizzle (128B rows, 8x16B chunks): LDS[r][c] = G[r][c^(r&7)]; store
// side linear GLL dest, source chunk (t&7)^((t>>3)&7); read side chunk
// (4ks+quad)^(l16&7) -> 8-lane group hits all 32 banks once; wave64 = 2
// lanes/bank = free.  Measured conflict-free (counter = hist floor 8567313).
__global__ __launch_bounds__(1024, 4) void gemm_hist256(
    const half_t* __restrict__ xh, const half_t* __restrict__ wh,
    const float* __restrict__ mins, const float* __restrict__ maxs,
    int* __restrict__ ghist)
{
  __shared__ __align__(16) char ldsA[2 * 32768];   // 2 bufs x 256 rows x 128 B
  __shared__ __align__(16) char ldsB[2 * 32768];
  __shared__ int shist[256 * HSTRIDE];             // 21.5 KB (total 152.6 KB)

  const int t    = threadIdx.x;
  const int lane = t & 63;
  const int wv   = t >> 6;           // 0..15
  const int wm   = wv >> 2;          // 0..3
  const int wn   = wv & 3;           // 0..3
  const int l16  = lane & 15;
  const int quad = lane >> 4;

  // XCD-aware bijective swizzle: 1600 blocks = 8 XCDs x 200
  const int bid = blockIdx.x;
  const int wg  = (bid & 7) * 200 + (bid >> 3);
  const int ct  = wg / 64;                 // 0..24 col-tiles
  const int rt  = wg - ct * 64;            // 0..63 row-tiles
  const int colBase = ct * 256;
  const int rowBase = rt * 256;

  for (int i = t; i < 256 * HSTRIDE; i += 1024) shist[i] = 0;

  // Fragment read bases, one per ks (k-slice of 32).  Row stride 128 B.
  // chunk(ks) = (4*ks + quad) ^ (l16 & 7).
  const char* pA0 = ldsA + (wm * 64 + l16) * 128 + (((0 + quad) ^ (l16 & 7)) * 16);
  const char* pA1 = ldsA + (wm * 64 + l16) * 128 + (((4 + quad) ^ (l16 & 7)) * 16);
  const char* pB0 = ldsB + (wn * 64 + l16) * 128 + (((0 + quad) ^ (l16 & 7)) * 16);
  const char* pB1 = ldsB + (wn * 64 + l16) * 128 + (((4 + quad) ^ (l16 & 7)) * 16);

  // Staging: thread t owns linear 16B slot t of each 16KB half (rows 0-127);
  // second GLL covers rows 128-255.  Source chunk = (t&7)^((t>>3)&7).
  const int gOff = (t >> 3) * K_DIM + (((t & 7) ^ ((t >> 3) & 7)) * 8);  // elems
  const int wvD  = wv * 1024;   // wave-uniform LDS base (HW adds lane*16)

  const half_t* xS = xh + (size_t)rowBase * K_DIM + gOff;
  const half_t* wS = wh + (size_t)colBase * K_DIM + gOff;

  f32x4 acc[4][4];
#pragma unroll
  for (int m = 0; m < 4; ++m)
#pragma unroll
    for (int n = 0; n < 4; ++n) acc[m][n] = (f32x4){0.f, 0.f, 0.f, 0.f};

  half8 aF[4], bF[4];

#define MFMA16()                                                             \
  _Pragma("unroll") for (int mf = 0; mf < 4; ++mf)                           \
  _Pragma("unroll") for (int nf = 0; nf < 4; ++nf)                           \
    acc[mf][nf] = __builtin_amdgcn_mfma_f32_16x16x32_f16(                    \
        aF[mf], bF[nf], acc[mf][nf], 0, 0, 0);

  // Prologue: stage tile 0 -> buf0 (4 GLL); retire + publish.
  GLL(xS,          ldsA + wvD);
  GLL(xS + 131072, ldsA + 16384 + wvD);   // +128 rows (128*1024 elems)
  GLL(wS,          ldsB + wvD);
  GLL(wS + 131072, ldsB + 16384 + wvD);
  VMWAIT0(); BAR();

  // Loop-carried staging pointers: at tile t they point at k-offset
  // (t+1)*64 elements; advance +64 per tile.
  const half_t* xStg = xS + 64;
  const half_t* wStg = wS + 64;

  // PB = current tile's buf offset, PN = next tile's.  STG: stage t+1.
#define TILE(PB, PN, STG)                                                    \
  {                                                                          \
    if (STG) {                                                               \
      GLL(xStg,          ldsA + (PN) + wvD);                                 \
      GLL(xStg + 131072, ldsA + (PN) + 16384 + wvD);                         \
      GLL(wStg,          ldsB + (PN) + wvD);                                 \
      GLL(wStg + 131072, ldsB + (PN) + 16384 + wvD);                         \
      xStg += 64; wStg += 64;                                                \
    }                                                                        \
    _Pragma("unroll") for (int mf = 0; mf < 4; ++mf)                         \
      aF[mf] = *(const half8*)(pA0 + (PB) + mf * 2048);                      \
    _Pragma("unroll") for (int nf = 0; nf < 4; ++nf)                         \
      bF[nf] = *(const half8*)(pB0 + (PB) + nf * 2048);                      \
    SP1(); MFMA16(); SP0();                                                  \
    _Pragma("unroll") for (int mf = 0; mf < 4; ++mf)                         \
      aF[mf] = *(const half8*)(pA1 + (PB) + mf * 2048);                      \
    _Pragma("unroll") for (int nf = 0; nf < 4; ++nf)                         \
      bF[nf] = *(const half8*)(pB1 + (PB) + nf * 2048);                      \
    SP1(); MFMA16(); SP0();                                                  \
    VMWAIT0(); BAR();                                                        \
  }

  // 16 K-tiles; tiles 0..14 stage t+1, tile 15 computes only.
#pragma unroll 1
  for (int it = 0; it < 7; ++it) {
    TILE(0,     32768, 1);
    TILE(32768, 0,     1);
  }
  TILE(0,     32768, 1);   // t=14 (stages 15)
  TILE(32768, 0,     0);   // t=15

#undef TILE

  // Epilogue: bin 64 values/thread. torch.histc semantics: count iff
  // min<=v<=max; v==max -> last bin (trunc==floor since v-a>=0).
#pragma unroll
  for (int nf = 0; nf < 4; ++nf) {
    const int lc = wn * 64 + nf * 16 + l16;
    const float a = mins[colBase + lc], b = maxs[colBase + lc];
    const float sc = (float)NBINS / (b - a);
    int* colHist = &shist[lc * HSTRIDE];
#pragma unroll
    for (int mf = 0; mf < 4; ++mf) {
#pragma unroll
      for (int r = 0; r < 4; ++r) {
        float v = acc[mf][nf][r];
        if (v >= a && v <= b) {
          int bin = (int)((v - a) * sc);
          bin = bin > NBINS - 1 ? NBINS - 1 : bin;
          atomicAdd(&colHist[bin], 1);
        }
      }
    }
  }
  __syncthreads();
  for (int i = t; i < 256 * NBINS; i += 1024) {
    int col = i / NBINS, bin = i - col * NBINS;
    int v = shist[col * HSTRIDE + bin];
    if (v) atomicAdd(&ghist[colBase * NBINS + i], v);
  }
}

// ---------------- fallback (no workspace): fp32-staged 128x128 tile -------
__global__ __launch_bounds__(256) void gemm_hist_fb(
    const float* __restrict__ xf, const float* __restrict__ wf,
    const float* __restrict__ mins, const float* __restrict__ maxs,
    int* __restrict__ ghist)
{
  __shared__ __align__(16) half_t ldsA[4096];
  __shared__ __align__(16) half_t ldsB[4096];
  __shared__ int shist[128 * HSTRIDE];

  const int t     = threadIdx.x;
  const int lane  = t & 63;
  const int wv    = t >> 6;
  const int waveM = wv >> 1;
  const int waveN = wv & 1;
  const int l16   = lane & 15;
  const int quad  = lane >> 4;
  const int colBase = blockIdx.x * 128;

  for (int i = t; i < 128 * HSTRIDE; i += 256) shist[i] = 0;

  float mn[4], mx[4], inv[4];
  int lcol[4];
#pragma unroll
  for (int nt = 0; nt < 4; ++nt) {
    int lc = waveN * 64 + nt * 16 + l16;
    lcol[nt] = lc;
    float a = mins[colBase + lc], b = maxs[colBase + lc];
    mn[nt] = a; mx[nt] = b;
    inv[nt] = (float)NBINS / (b - a);
  }

  int aOff[4], bOff[4];
#pragma unroll
  for (int mt = 0; mt < 4; ++mt) {
    int m = waveM * 64 + mt * 16 + l16;
    aOff[mt] = (m * 4 + (quad ^ ((m >> 1) & 3))) * 8;
  }
#pragma unroll
  for (int nt = 0; nt < 4; ++nt) {
    int n = waveN * 64 + nt * 16 + l16;
    bOff[nt] = (n * 4 + (quad ^ ((n >> 1) & 3))) * 8;
  }

  for (int rt = blockIdx.y; rt < S_DIM / 128; rt += gridDim.y) {
    const int rowBase = rt * 128;
    f32x4 acc[4][4];
#pragma unroll
    for (int mt = 0; mt < 4; ++mt)
#pragma unroll
      for (int nt = 0; nt < 4; ++nt) acc[mt][nt] = (f32x4){0.f, 0.f, 0.f, 0.f};

    for (int kt = 0; kt < K_DIM; kt += 32) {
      __syncthreads();
#pragma unroll
      for (int i = 0; i < 2; ++i) {
        const int seg = t + i * 256;
        const int row = seg >> 2;
        const int kch = (seg & 3) ^ ((row >> 1) & 3);
        const float* ga = xf + (size_t)(rowBase + row) * K_DIM + kt + kch * 8;
        float4 v0 = ((const float4*)ga)[0];
        float4 v1 = ((const float4*)ga)[1];
        half8 h = { (half_t)v0.x, (half_t)v0.y, (half_t)v0.z, (half_t)v0.w,
                    (half_t)v1.x, (half_t)v1.y, (half_t)v1.z, (half_t)v1.w };
        *(half8*)&ldsA[seg * 8] = h;
        const float* gb = wf + (size_t)(colBase + row) * K_DIM + kt + kch * 8;
        float4 u0 = ((const float4*)gb)[0];
        float4 u1 = ((const float4*)gb)[1];
        half8 g = { (half_t)u0.x, (half_t)u0.y, (half_t)u0.z, (half_t)u0.w,
                    (half_t)u1.x, (half_t)u1.y, (half_t)u1.z, (half_t)u1.w };
        *(half8*)&ldsB[seg * 8] = g;
      }
      __syncthreads();
      {
        half8 aFf[4], bFf[4];
#pragma unroll
        for (int mt = 0; mt < 4; ++mt) aFf[mt] = *(const half8*)&ldsA[aOff[mt]];
#pragma unroll
        for (int nt = 0; nt < 4; ++nt) bFf[nt] = *(const half8*)&ldsB[bOff[nt]];
#pragma unroll
        for (int mt = 0; mt < 4; ++mt)
#pragma unroll
          for (int nt = 0; nt < 4; ++nt)
            acc[mt][nt] = __builtin_amdgcn_mfma_f32_16x16x32_f16(
                aFf[mt], bFf[nt], acc[mt][nt], 0, 0, 0);
      }
    }

#pragma unroll
    for (int nt = 0; nt < 4; ++nt) {
      const float a = mn[nt], b = mx[nt], sc = inv[nt];
      int* colHist = &shist[lcol[nt] * HSTRIDE];
#pragma unroll
      for (int mt = 0; mt < 4; ++mt) {
#pragma unroll
        for (int r = 0; r < 4; ++r) {
          float v = acc[mt][nt][r];
          if (v >= a && v <= b) {
            int bin = (int)((v - a) * sc);
            bin = bin > NBINS - 1 ? NBINS - 1 : bin;
            atomicAdd(&colHist[bin], 1);
          }
        }
      }
    }
  }

  __syncthreads();
  for (int i = t; i < 128 * NBINS; i += 256) {
    int col = i / NBINS, bin = i - col * NBINS;
    int v = shist[col * HSTRIDE + bin];
    if (v) atomicAdd(&ghist[colBase * NBINS + i], v);
  }
}

// ---------------- L2 normalize per group of 20 bins (in place) ------------
__global__ void normalize_kernel(const int* __restrict__ hist, float* __restrict__ out) {
  int g = blockIdx.x * blockDim.x + threadIdx.x;
  if (g >= D_DIM) return;
  const int base = g * NBINS;
  float v[NBINS];
  float ss = 0.f;
#pragma unroll
  for (int i = 0; i < NBINS; ++i) { v[i] = (float)hist[base + i]; ss += v[i] * v[i]; }
  float sc = 1.0f / fmaxf(sqrtf(ss), 1e-12f);
#pragma unroll
  for (int i = 0; i < NBINS; ++i) out[base + i] = v[i] * sc;
}

extern "C" void kernel_launch(void* const* d_in, const int* in_sizes, int n_in,
                              void* d_out, int out_size, void* d_ws, size_t ws_size,
                              hipStream_t stream) {
  const float* x    = (const float*)d_in[0];
  const float* W    = (const float*)d_in[1];
  const float* mins = (const float*)d_in[2];
  const float* maxs = (const float*)d_in[3];
  float* out = (float*)d_out;

  const size_t xh_elems = (size_t)S_DIM * K_DIM;
  const size_t wh_elems = (size_t)D_DIM * K_DIM;
  const size_t need = (xh_elems + wh_elems) * sizeof(half_t);

  if (ws_size >= need) {
    half_t* xh = (half_t*)d_ws;
    half_t* wh = xh + xh_elems;
    int n4x = (int)(xh_elems / 4), n4w = (int)(wh_elems / 4);
    // cvt also zeroes d_out (re-poisoned 0xAA between runs)
    cvt_fused<<<2048, 256, 0, stream>>>(
        (const float4*)x, (unsigned long long*)xh, n4x,
        (const float4*)W, (unsigned long long*)wh, n4w,
        (float4*)d_out, out_size / 4);
    gemm_hist256<<<dim3(1600), 1024, 0, stream>>>(xh, wh, mins, maxs, (int*)d_out);
  } else {
    hipMemsetAsync(d_out, 0, (size_t)out_size * sizeof(float), stream);
    gemm_hist_fb<<<dim3(D_DIM / 128, 64), 256, 0, stream>>>(
        x, W, mins, maxs, (int*)d_out);
  }

  normalize_kernel<<<(D_DIM + 255) / 256, 256, 0, stream>>>((int*)d_out, out);
}